// Round 2
// baseline (1006.301 us; speedup 1.0000x reference)
//
#include <hip/hip_runtime.h>

#define B_   2
#define L_   2048
#define D_   1024
#define H_   16
#define DH_  64
#define M_TOT (B_ * L_)   // 4096

typedef __attribute__((ext_vector_type(8))) __bf16 bf16x8;
typedef __attribute__((ext_vector_type(4))) float f32x4;
typedef __attribute__((ext_vector_type(8))) unsigned short u16x8;

// round-to-nearest-even fp32 -> bf16
__device__ __forceinline__ unsigned short f2bf(float f) {
    unsigned int u = __float_as_uint(f);
    u += 0x7fffu + ((u >> 16) & 1u);
    return (unsigned short)(u >> 16);
}
__device__ __forceinline__ float bf2f(unsigned short u) {
    return __uint_as_float(((unsigned int)u) << 16);
}

// async 16B global -> LDS (dest = wave-uniform base + lane*16)
__device__ __forceinline__ void gload_lds16(const void* g, void* l) {
    __builtin_amdgcn_global_load_lds(
        (__attribute__((address_space(1))) void*)(void*)g,
        (__attribute__((address_space(3))) void*)l, 16, 0, 0);
}

// ---------------------------------------------------------------------------
// casts
// ---------------------------------------------------------------------------
__global__ __launch_bounds__(256) void cast_in(const float* __restrict__ src,
                                               u16x8* __restrict__ dst)
{
    const int i = blockIdx.x * 256 + threadIdx.x;   // 8 elems per thread
    const float4* s = (const float4*)src;
    float4 a = s[2 * i], b = s[2 * i + 1];
    u16x8 w;
    w[0] = f2bf(a.x); w[1] = f2bf(a.y); w[2] = f2bf(a.z); w[3] = f2bf(a.w);
    w[4] = f2bf(b.x); w[5] = f2bf(b.y); w[6] = f2bf(b.z); w[7] = f2bf(b.w);
    dst[i] = w;
}

__global__ __launch_bounds__(256) void cast_w4(const float* __restrict__ Wq,
                                               const float* __restrict__ Wk,
                                               const float* __restrict__ Wv,
                                               const float* __restrict__ Wo,
                                               u16x8* __restrict__ dst)
{
    const int y = blockIdx.y;
    const float* src = (y == 0) ? Wq : (y == 1) ? Wk : (y == 2) ? Wv : Wo;
    const int i = blockIdx.x * 256 + threadIdx.x;
    const float4* s = (const float4*)src;
    float4 a = s[2 * i], b = s[2 * i + 1];
    u16x8 w;
    w[0] = f2bf(a.x); w[1] = f2bf(a.y); w[2] = f2bf(a.z); w[3] = f2bf(a.w);
    w[4] = f2bf(b.x); w[5] = f2bf(b.y); w[6] = f2bf(b.z); w[7] = f2bf(b.w);
    dst[(size_t)y * (D_ * D_ / 8) + i] = w;
}

// ---------------------------------------------------------------------------
// NT MFMA GEMM: C[M,N] = A[M,K](bf16) * W[N,K]^T(bf16) + bias[N]
// 128x128 tile, BK=64, 256 threads = 4 waves (2x2), 64x64 per wave.
// LDS swizzle: chunk (row, kc) holds global k-chunk kc^(row&7); read re-XORs.
// ---------------------------------------------------------------------------
template<bool F32OUT>
__global__ __launch_bounds__(256) void gemm_nt_mfma(
    const unsigned short* __restrict__ A, const unsigned short* __restrict__ W,
    const float* __restrict__ bias, void* __restrict__ Cout, int K, int N)
{
    __shared__ __align__(16) unsigned short As[128 * 64];
    __shared__ __align__(16) unsigned short Bs[128 * 64];
    const int tid  = threadIdx.x;
    const int bm   = blockIdx.x * 128;
    const int bn   = blockIdx.y * 128;
    const int lane = tid & 63, wid = tid >> 6;
    const int wm   = (wid >> 1) * 64, wn = (wid & 1) * 64;
    const int kg   = lane >> 4, lr = lane & 15;
    const int swz  = lr & 7;

    f32x4 zero = {0.f, 0.f, 0.f, 0.f};
    f32x4 acc[4][4];
    #pragma unroll
    for (int m = 0; m < 4; ++m)
        #pragma unroll
        for (int n = 0; n < 4; ++n) acc[m][n] = zero;

    for (int k0 = 0; k0 < K; k0 += 64) {
        __syncthreads();                      // readers done with LDS
        #pragma unroll
        for (int i = 0; i < 4; ++i) {
            int c   = i * 256 + tid;          // 1024 chunks of 16B per tile
            int row = c >> 3;
            int c8  = (c & 7) ^ (row & 7);    // pre-swizzled source chunk
            gload_lds16(A + (size_t)(bm + row) * K + k0 + c8 * 8, (char*)As + c * 16);
            gload_lds16(W + (size_t)(bn + row) * K + k0 + c8 * 8, (char*)Bs + c * 16);
        }
        __syncthreads();                      // drains vmcnt before barrier
        #pragma unroll
        for (int ks = 0; ks < 2; ++ks) {
            bf16x8 af[4], bfr[4];
            #pragma unroll
            for (int m = 0; m < 4; ++m)
                af[m] = *(const bf16x8*)((const char*)As +
                        (wm + m * 16 + lr) * 128 + (((ks * 4 + kg) ^ swz) << 4));
            #pragma unroll
            for (int n = 0; n < 4; ++n)
                bfr[n] = *(const bf16x8*)((const char*)Bs +
                        (wn + n * 16 + lr) * 128 + (((ks * 4 + kg) ^ swz) << 4));
            #pragma unroll
            for (int m = 0; m < 4; ++m)
                #pragma unroll
                for (int n = 0; n < 4; ++n)
                    acc[m][n] = __builtin_amdgcn_mfma_f32_16x16x32_bf16(
                        af[m], bfr[n], acc[m][n], 0, 0, 0);
        }
    }

    // C/D layout: col = lane&15, row = (lane>>4)*4 + reg
    #pragma unroll
    for (int n = 0; n < 4; ++n) {
        const int col = bn + wn + n * 16 + lr;
        const float bv = bias[col];
        #pragma unroll
        for (int m = 0; m < 4; ++m) {
            const int row0 = bm + wm + m * 16 + kg * 4;
            #pragma unroll
            for (int r = 0; r < 4; ++r) {
                float val = acc[m][n][r] + bv;
                if (F32OUT)
                    ((float*)Cout)[(size_t)(row0 + r) * N + col] = val;
                else
                    ((unsigned short*)Cout)[(size_t)(row0 + r) * N + col] = f2bf(val);
            }
        }
    }
}

// ---------------------------------------------------------------------------
// Scores: per z=(b,h): E[q,kv] = exp( exp(ls)*(qn_h . kn_h) + lb ), fp32 out.
// |S| <= e + |lb| (normalized q,k) so no max subtraction needed.
// Also emits per-row partial sums into Sp[z][row][by] (own slot, no atomics).
// ---------------------------------------------------------------------------
__global__ __launch_bounds__(256) void gemm_scores_mfma(
    const unsigned short* __restrict__ qn, const unsigned short* __restrict__ kn,
    const float* __restrict__ ls, const float* __restrict__ lb,
    float* __restrict__ attn, float* __restrict__ Sp)
{
    __shared__ __align__(16) unsigned short As[128 * 64];
    __shared__ __align__(16) unsigned short Bs[128 * 64];
    __shared__ float rsum[2][128];
    const int z = blockIdx.z, b = z >> 4, h = z & 15;
    const unsigned short* Ap = qn + (size_t)b * L_ * D_ + h * DH_;  // lda = D_
    const unsigned short* Bp = kn + (size_t)b * L_ * D_ + h * DH_;
    float* Cp = attn + (size_t)z * L_ * L_;

    const int tid  = threadIdx.x;
    const int bm   = blockIdx.x * 128;
    const int bn   = blockIdx.y * 128;
    const int lane = tid & 63, wid = tid >> 6;
    const int wm   = (wid >> 1) * 64, wn = (wid & 1) * 64;
    const int kg   = lane >> 4, lr = lane & 15;
    const int swz  = lr & 7;

    f32x4 zero = {0.f, 0.f, 0.f, 0.f};
    f32x4 acc[4][4];
    #pragma unroll
    for (int m = 0; m < 4; ++m)
        #pragma unroll
        for (int n = 0; n < 4; ++n) acc[m][n] = zero;

    #pragma unroll
    for (int i = 0; i < 4; ++i) {
        int c   = i * 256 + tid;
        int row = c >> 3;
        int c8  = (c & 7) ^ (row & 7);
        gload_lds16(Ap + (size_t)(bm + row) * D_ + c8 * 8, (char*)As + c * 16);
        gload_lds16(Bp + (size_t)(bn + row) * D_ + c8 * 8, (char*)Bs + c * 16);
    }
    __syncthreads();
    #pragma unroll
    for (int ks = 0; ks < 2; ++ks) {
        bf16x8 af[4], bfr[4];
        #pragma unroll
        for (int m = 0; m < 4; ++m)
            af[m] = *(const bf16x8*)((const char*)As +
                    (wm + m * 16 + lr) * 128 + (((ks * 4 + kg) ^ swz) << 4));
        #pragma unroll
        for (int n = 0; n < 4; ++n)
            bfr[n] = *(const bf16x8*)((const char*)Bs +
                    (wn + n * 16 + lr) * 128 + (((ks * 4 + kg) ^ swz) << 4));
        #pragma unroll
        for (int m = 0; m < 4; ++m)
            #pragma unroll
            for (int n = 0; n < 4; ++n)
                acc[m][n] = __builtin_amdgcn_mfma_f32_16x16x32_bf16(
                    af[m], bfr[n], acc[m][n], 0, 0, 0);
    }

    const float scale = expf(ls[0]);
    const float sb = lb[0];
    float ps[4][4] = {};                      // partial row sums (over this block's cols)
    #pragma unroll
    for (int n = 0; n < 4; ++n) {
        const int col = bn + wn + n * 16 + lr;
        #pragma unroll
        for (int m = 0; m < 4; ++m) {
            const int row0 = bm + wm + m * 16 + kg * 4;
            #pragma unroll
            for (int r = 0; r < 4; ++r) {
                float e = __expf(acc[m][n][r] * scale + sb);
                Cp[(size_t)(row0 + r) * L_ + col] = e;
                ps[m][r] += e;
            }
        }
    }
    // reduce over lr (lane bits 0..3); kg groups are different rows
    #pragma unroll
    for (int m = 0; m < 4; ++m)
        #pragma unroll
        for (int r = 0; r < 4; ++r) {
            float s = ps[m][r];
            s += __shfl_xor(s, 1); s += __shfl_xor(s, 2);
            s += __shfl_xor(s, 4); s += __shfl_xor(s, 8);
            ps[m][r] = s;
        }
    if (lr == 0) {
        #pragma unroll
        for (int m = 0; m < 4; ++m)
            #pragma unroll
            for (int r = 0; r < 4; ++r)
                rsum[wid & 1][wm + m * 16 + kg * 4 + r] = ps[m][r];
    }
    __syncthreads();
    if (tid < 128)
        Sp[((size_t)z * L_ + bm + tid) * 16 + blockIdx.y] = rsum[0][tid] + rsum[1][tid];
}

// ---------------------------------------------------------------------------
// PV + softmax-normalize: per z:
//   inv[row] = 1 / sum_by Sp[z][row][by]
//   P = E * inv   -> written back to attn (the checked output)
//   ctx[q,d] = sum_kv P[q,kv] * V[kv,d]   (bf16 MFMA, Vt is [z][DH][L])
// ---------------------------------------------------------------------------
__global__ __launch_bounds__(256) void gemm_pv_mfma(
    float* __restrict__ attn, const unsigned short* __restrict__ Vt,
    const float* __restrict__ Sp, unsigned short* __restrict__ ctx)
{
    __shared__ __align__(16) unsigned short As[128 * 64];
    __shared__ __align__(16) unsigned short Bs[64 * 64];
    __shared__ float invs[128];
    const int z = blockIdx.z, b = z >> 4, h = z & 15;
    float* Ap = attn + (size_t)z * L_ * L_;
    const unsigned short* Bp = Vt + (size_t)z * DH_ * L_;
    unsigned short* Cp = ctx + (size_t)b * L_ * D_ + h * DH_;

    const int tid  = threadIdx.x;
    const int bm   = blockIdx.x * 128;
    const int lane = tid & 63, wid = tid >> 6;
    const int wm   = (wid >> 1) * 64, wn = (wid & 1) * 32;
    const int kg   = lane >> 4, lr = lane & 15;
    const int swz  = lr & 7;

    if (tid < 128) {
        const float* p = Sp + ((size_t)z * L_ + bm + tid) * 16;
        float s = 0.f;
        #pragma unroll
        for (int i = 0; i < 16; ++i) s += p[i];
        invs[tid] = 1.0f / s;
    }
    __syncthreads();

    f32x4 zero = {0.f, 0.f, 0.f, 0.f};
    f32x4 acc[4][2];
    #pragma unroll
    for (int m = 0; m < 4; ++m) { acc[m][0] = zero; acc[m][1] = zero; }

    for (int k0 = 0; k0 < L_; k0 += 64) {
        // issue E loads early (latency hides under barrier + B-stage)
        float4 a0[4], a1[4];
        float iv[4];
        #pragma unroll
        for (int i = 0; i < 4; ++i) {
            int c   = i * 256 + tid;
            int row = c >> 3;
            int c8  = (c & 7) ^ (row & 7);
            float* src = Ap + (size_t)(bm + row) * L_ + k0 + c8 * 8;
            a0[i] = *(const float4*)src;
            a1[i] = *(const float4*)(src + 4);
            iv[i] = invs[row];
        }
        __syncthreads();                      // readers done with LDS
        #pragma unroll
        for (int i = 0; i < 2; ++i) {         // Vt tile: 64 rows x 64 k
            int c   = i * 256 + tid;
            int row = c >> 3;
            int c8  = (c & 7) ^ (row & 7);
            gload_lds16(Bp + (size_t)row * L_ + k0 + c8 * 8, (char*)Bs + c * 16);
        }
        #pragma unroll
        for (int i = 0; i < 4; ++i) {         // normalize, write attn, stage bf16
            int c   = i * 256 + tid;
            int row = c >> 3;
            int c8  = (c & 7) ^ (row & 7);
            a0[i].x *= iv[i]; a0[i].y *= iv[i]; a0[i].z *= iv[i]; a0[i].w *= iv[i];
            a1[i].x *= iv[i]; a1[i].y *= iv[i]; a1[i].z *= iv[i]; a1[i].w *= iv[i];
            float* dst = Ap + (size_t)(bm + row) * L_ + k0 + c8 * 8;
            *(float4*)dst = a0[i];
            *(float4*)(dst + 4) = a1[i];
            u16x8 w;
            w[0] = f2bf(a0[i].x); w[1] = f2bf(a0[i].y);
            w[2] = f2bf(a0[i].z); w[3] = f2bf(a0[i].w);
            w[4] = f2bf(a1[i].x); w[5] = f2bf(a1[i].y);
            w[6] = f2bf(a1[i].z); w[7] = f2bf(a1[i].w);
            *(u16x8*)((char*)As + c * 16) = w;
        }
        __syncthreads();
        #pragma unroll
        for (int ks = 0; ks < 2; ++ks) {
            bf16x8 af[4], bfr[2];
            #pragma unroll
            for (int m = 0; m < 4; ++m)
                af[m] = *(const bf16x8*)((const char*)As +
                        (wm + m * 16 + lr) * 128 + (((ks * 4 + kg) ^ swz) << 4));
            #pragma unroll
            for (int n = 0; n < 2; ++n)
                bfr[n] = *(const bf16x8*)((const char*)Bs +
                        (wn + n * 16 + lr) * 128 + (((ks * 4 + kg) ^ swz) << 4));
            #pragma unroll
            for (int m = 0; m < 4; ++m)
                #pragma unroll
                for (int n = 0; n < 2; ++n)
                    acc[m][n] = __builtin_amdgcn_mfma_f32_16x16x32_bf16(
                        af[m], bfr[n], acc[m][n], 0, 0, 0);
        }
    }

    #pragma unroll
    for (int n = 0; n < 2; ++n) {
        const int col = wn + n * 16 + lr;     // 0..63 within head
        #pragma unroll
        for (int m = 0; m < 4; ++m) {
            const int row0 = bm + wm + m * 16 + kg * 4;
            #pragma unroll
            for (int r = 0; r < 4; ++r)
                Cp[(size_t)(row0 + r) * D_ + col] = f2bf(acc[m][n][r]);
        }
    }
}

// ---------------------------------------------------------------------------
// per-head transpose: v8 [B*L, D] -> Vt [B*H, DH, L]
// ---------------------------------------------------------------------------
__global__ __launch_bounds__(256) void transpose_v(
    const unsigned short* __restrict__ v8, unsigned short* __restrict__ Vt)
{
    __shared__ unsigned short tile[64][66];
    const int z = blockIdx.y, b = z >> 4, h = z & 15;
    const int t0 = blockIdx.x * 64;
    const unsigned short* src = v8 + ((size_t)(b * L_ + t0)) * D_ + h * DH_;
    unsigned short* dst = Vt + (size_t)z * DH_ * L_ + t0;
    const int t = threadIdx.x;
    #pragma unroll
    for (int i = 0; i < 2; ++i) {
        int c = i * 256 + t;
        int r = c >> 3, c8 = c & 7;
        u16x8 v = *(const u16x8*)(src + (size_t)r * D_ + c8 * 8);
        #pragma unroll
        for (int e = 0; e < 8; ++e) tile[r][c8 * 8 + e] = v[e];
    }
    __syncthreads();
    #pragma unroll
    for (int i = 0; i < 2; ++i) {
        int c = i * 256 + t;
        int d = c >> 3, c8 = c & 7;
        u16x8 v;
        #pragma unroll
        for (int e = 0; e < 8; ++e) v[e] = tile[c8 * 8 + e][d];
        *(u16x8*)(dst + (size_t)d * L_ + c8 * 8) = v;
    }
}

// ---------------------------------------------------------------------------
// in-place row L2-norm over D_ = 1024 bf16 (one block per row)
// ---------------------------------------------------------------------------
__global__ __launch_bounds__(256) void l2norm_bf16(unsigned short* __restrict__ x)
{
    unsigned short* row = x + (size_t)blockIdx.x * D_;
    const int tid = threadIdx.x;
    ushort4 v = ((ushort4*)row)[tid];
    float f0 = bf2f(v.x), f1 = bf2f(v.y), f2 = bf2f(v.z), f3 = bf2f(v.w);
    float ss = f0 * f0 + f1 * f1 + f2 * f2 + f3 * f3;
    #pragma unroll
    for (int off = 32; off >= 1; off >>= 1)
        ss += __shfl_xor(ss, off);
    __shared__ float red[4];
    const int lane = tid & 63, wid = tid >> 6;
    if (lane == 0) red[wid] = ss;
    __syncthreads();
    ss = red[0] + red[1] + red[2] + red[3];
    const float inv = rsqrtf(ss);
    ushort4 o;
    o.x = f2bf(f0 * inv); o.y = f2bf(f1 * inv);
    o.z = f2bf(f2 * inv); o.w = f2bf(f3 * inv);
    ((ushort4*)row)[tid] = o;
}

// ---------------------------------------------------------------------------
extern "C" void kernel_launch(void* const* d_in, const int* in_sizes, int n_in,
                              void* d_out, int out_size, void* d_ws, size_t ws_size,
                              hipStream_t stream)
{
    const float* query = (const float*)d_in[0];
    const float* key_  = (const float*)d_in[1];
    const float* value = (const float*)d_in[2];
    const float* ls    = (const float*)d_in[3];
    const float* lb    = (const float*)d_in[4];
    const float* Wq    = (const float*)d_in[5];
    const float* bq    = (const float*)d_in[6];
    const float* Wk    = (const float*)d_in[7];
    const float* bk    = (const float*)d_in[8];
    const float* Wv    = (const float*)d_in[9];
    const float* bv    = (const float*)d_in[10];
    const float* Wo    = (const float*)d_in[11];
    const float* bo    = (const float*)d_in[12];

    float* out  = (float*)d_out;                     // [B, L, D]
    float* attn = out + (size_t)M_TOT * D_;          // [B, H, L, L] fp32

    // workspace: 48 MB total
    unsigned short* xb = (unsigned short*)d_ws;                  // 8 MB cast input
    unsigned short* Wb = xb + (size_t)M_TOT * D_;                // 8 MB (4 x 1M bf16)
    unsigned short* q8 = Wb + (size_t)4 * D_ * D_;               // 8 MB
    unsigned short* k8 = q8 + (size_t)M_TOT * D_;                // 8 MB
    unsigned short* v8 = k8 + (size_t)M_TOT * D_;                // 8 MB
    unsigned short* Vt = v8 + (size_t)M_TOT * D_;                // 8 MB
    unsigned short* ctxb = xb;                                   // reuse (xb dead)
    float* Sp = (float*)v8;       // 4 MB partial sums; v8 dead after transpose_v

    dim3 blk(256);
    const dim3 gproj(M_TOT / 128, D_ / 128);         // 32 x 8

    cast_w4<<<dim3(D_ * D_ / 8 / 256, 4), blk, 0, stream>>>(Wq, Wk, Wv, Wo, (u16x8*)Wb);

    cast_in<<<M_TOT * D_ / 8 / 256, blk, 0, stream>>>(query, (u16x8*)xb);
    gemm_nt_mfma<false><<<gproj, blk, 0, stream>>>(xb, Wb + 0 * (size_t)D_ * D_, bq, q8, D_, D_);
    cast_in<<<M_TOT * D_ / 8 / 256, blk, 0, stream>>>(key_, (u16x8*)xb);
    gemm_nt_mfma<false><<<gproj, blk, 0, stream>>>(xb, Wb + 1 * (size_t)D_ * D_, bk, k8, D_, D_);
    cast_in<<<M_TOT * D_ / 8 / 256, blk, 0, stream>>>(value, (u16x8*)xb);
    gemm_nt_mfma<false><<<gproj, blk, 0, stream>>>(xb, Wb + 2 * (size_t)D_ * D_, bv, v8, D_, D_);

    l2norm_bf16<<<dim3(M_TOT), blk, 0, stream>>>(q8);
    l2norm_bf16<<<dim3(M_TOT), blk, 0, stream>>>(k8);

    transpose_v<<<dim3(L_ / 64, B_ * H_), blk, 0, stream>>>(v8, Vt);

    gemm_scores_mfma<<<dim3(L_ / 128, L_ / 128, B_ * H_), blk, 0, stream>>>(
        q8, k8, ls, lb, attn, Sp);

    gemm_pv_mfma<<<dim3(L_ / 128, 1, B_ * H_), blk, 0, stream>>>(attn, Vt, Sp, ctxb);

    gemm_nt_mfma<true><<<gproj, blk, 0, stream>>>(ctxb, Wb + 3 * (size_t)D_ * D_, bo, out, D_, D_);
}

// Round 3
// 826.547 us; speedup vs baseline: 1.2175x; 1.2175x over previous
//
#include <hip/hip_runtime.h>

#define B_   2
#define L_   2048
#define D_   1024
#define H_   16
#define DH_  64
#define M_TOT (B_ * L_)   // 4096

typedef __attribute__((ext_vector_type(8))) __bf16 bf16x8;
typedef __attribute__((ext_vector_type(4))) float f32x4;
typedef __attribute__((ext_vector_type(8))) unsigned short u16x8;

// round-to-nearest-even fp32 -> bf16
__device__ __forceinline__ unsigned short f2bf(float f) {
    unsigned int u = __float_as_uint(f);
    u += 0x7fffu + ((u >> 16) & 1u);
    return (unsigned short)(u >> 16);
}
__device__ __forceinline__ float bf2f(unsigned short u) {
    return __uint_as_float(((unsigned int)u) << 16);
}

// async 16B global -> LDS (dest = wave-uniform base + lane*16)
__device__ __forceinline__ void gload_lds16(const void* g, void* l) {
    __builtin_amdgcn_global_load_lds(
        (__attribute__((address_space(1))) void*)(void*)g,
        (__attribute__((address_space(3))) void*)l, 16, 0, 0);
}

// ---------------------------------------------------------------------------
// casts
// ---------------------------------------------------------------------------
__global__ __launch_bounds__(256) void cast_in(const float* __restrict__ src,
                                               u16x8* __restrict__ dst)
{
    const int i = blockIdx.x * 256 + threadIdx.x;   // 8 elems per thread
    const float4* s = (const float4*)src;
    float4 a = s[2 * i], b = s[2 * i + 1];
    u16x8 w;
    w[0] = f2bf(a.x); w[1] = f2bf(a.y); w[2] = f2bf(a.z); w[3] = f2bf(a.w);
    w[4] = f2bf(b.x); w[5] = f2bf(b.y); w[6] = f2bf(b.z); w[7] = f2bf(b.w);
    dst[i] = w;
}

__global__ __launch_bounds__(256) void cast_w4(const float* __restrict__ Wq,
                                               const float* __restrict__ Wk,
                                               const float* __restrict__ Wv,
                                               const float* __restrict__ Wo,
                                               u16x8* __restrict__ dst)
{
    const int y = blockIdx.y;
    const float* src = (y == 0) ? Wq : (y == 1) ? Wk : (y == 2) ? Wv : Wo;
    const int i = blockIdx.x * 256 + threadIdx.x;
    const float4* s = (const float4*)src;
    float4 a = s[2 * i], b = s[2 * i + 1];
    u16x8 w;
    w[0] = f2bf(a.x); w[1] = f2bf(a.y); w[2] = f2bf(a.z); w[3] = f2bf(a.w);
    w[4] = f2bf(b.x); w[5] = f2bf(b.y); w[6] = f2bf(b.z); w[7] = f2bf(b.w);
    dst[(size_t)y * (D_ * D_ / 8) + i] = w;
}

// ---------------------------------------------------------------------------
// NT MFMA GEMM: C[M,N] = A[M,K](bf16) * W[N,K]^T(bf16) + bias[N]
// 128x128 tile, BK=64, 256 threads = 4 waves (2x2), 64x64 per wave.
// ---------------------------------------------------------------------------
template<bool F32OUT>
__global__ __launch_bounds__(256) void gemm_nt_mfma(
    const unsigned short* __restrict__ A, const unsigned short* __restrict__ W,
    const float* __restrict__ bias, void* __restrict__ Cout, int K, int N)
{
    __shared__ __align__(16) unsigned short As[128 * 64];
    __shared__ __align__(16) unsigned short Bs[128 * 64];
    const int tid  = threadIdx.x;
    const int bm   = blockIdx.x * 128;
    const int bn   = blockIdx.y * 128;
    const int lane = tid & 63, wid = tid >> 6;
    const int wm   = (wid >> 1) * 64, wn = (wid & 1) * 64;
    const int kg   = lane >> 4, lr = lane & 15;
    const int swz  = lr & 7;

    f32x4 zero = {0.f, 0.f, 0.f, 0.f};
    f32x4 acc[4][4];
    #pragma unroll
    for (int m = 0; m < 4; ++m)
        #pragma unroll
        for (int n = 0; n < 4; ++n) acc[m][n] = zero;

    for (int k0 = 0; k0 < K; k0 += 64) {
        __syncthreads();
        #pragma unroll
        for (int i = 0; i < 4; ++i) {
            int c   = i * 256 + tid;
            int row = c >> 3;
            int c8  = (c & 7) ^ (row & 7);
            gload_lds16(A + (size_t)(bm + row) * K + k0 + c8 * 8, (char*)As + c * 16);
            gload_lds16(W + (size_t)(bn + row) * K + k0 + c8 * 8, (char*)Bs + c * 16);
        }
        __syncthreads();
        #pragma unroll
        for (int ks = 0; ks < 2; ++ks) {
            bf16x8 af[4], bfr[4];
            #pragma unroll
            for (int m = 0; m < 4; ++m)
                af[m] = *(const bf16x8*)((const char*)As +
                        (wm + m * 16 + lr) * 128 + (((ks * 4 + kg) ^ swz) << 4));
            #pragma unroll
            for (int n = 0; n < 4; ++n)
                bfr[n] = *(const bf16x8*)((const char*)Bs +
                        (wn + n * 16 + lr) * 128 + (((ks * 4 + kg) ^ swz) << 4));
            #pragma unroll
            for (int m = 0; m < 4; ++m)
                #pragma unroll
                for (int n = 0; n < 4; ++n)
                    acc[m][n] = __builtin_amdgcn_mfma_f32_16x16x32_bf16(
                        af[m], bfr[n], acc[m][n], 0, 0, 0);
        }
    }

    // C/D layout: col = lane&15, row = (lane>>4)*4 + reg
    #pragma unroll
    for (int n = 0; n < 4; ++n) {
        const int col = bn + wn + n * 16 + lr;
        const float bv = bias[col];
        #pragma unroll
        for (int m = 0; m < 4; ++m) {
            const int row0 = bm + wm + m * 16 + kg * 4;
            #pragma unroll
            for (int r = 0; r < 4; ++r) {
                float val = acc[m][n][r] + bv;
                if (F32OUT)
                    ((float*)Cout)[(size_t)(row0 + r) * N + col] = val;
                else
                    ((unsigned short*)Cout)[(size_t)(row0 + r) * N + col] = f2bf(val);
            }
        }
    }
}

// ---------------------------------------------------------------------------
// Pass 1: per (z, q-tile 128): row sums of exp(scale*(q.k)+bias) over all kv.
// No attn traffic — recompute is cheap (MFMA). sums layout [z][L].
// ---------------------------------------------------------------------------
__global__ __launch_bounds__(256) void attn_sums(
    const unsigned short* __restrict__ qn, const unsigned short* __restrict__ kn,
    const float* __restrict__ ls, const float* __restrict__ lb,
    float* __restrict__ sums)
{
    __shared__ __align__(16) unsigned short Qs[128 * 64];
    __shared__ __align__(16) unsigned short Ks[128 * 64];
    __shared__ float red[2][128];
    const int z = blockIdx.y, b = z >> 4, h = z & 15;
    const unsigned short* Qp = qn + (size_t)b * L_ * D_ + h * DH_;
    const unsigned short* Kp = kn + (size_t)b * L_ * D_ + h * DH_;

    const int tid  = threadIdx.x;
    const int bm   = blockIdx.x * 128;
    const int lane = tid & 63, wid = tid >> 6;
    const int wq   = wid >> 1, wkv = wid & 1;
    const int kg   = lane >> 4, lr = lane & 15;
    const int swz  = lr & 7;

    #pragma unroll
    for (int i = 0; i < 4; ++i) {
        int c = i * 256 + tid, row = c >> 3, c8 = (c & 7) ^ (row & 7);
        gload_lds16(Qp + (size_t)(bm + row) * D_ + c8 * 8, (char*)Qs + c * 16);
    }

    const float scale = expf(ls[0]);
    const float sb = lb[0];
    f32x4 zero = {0.f, 0.f, 0.f, 0.f};
    float rs[4][4] = {};

    for (int kv0 = 0; kv0 < L_; kv0 += 128) {
        __syncthreads();
        #pragma unroll
        for (int i = 0; i < 4; ++i) {
            int c = i * 256 + tid, row = c >> 3, c8 = (c & 7) ^ (row & 7);
            gload_lds16(Kp + (size_t)(kv0 + row) * D_ + c8 * 8, (char*)Ks + c * 16);
        }
        __syncthreads();
        f32x4 s[4][4];
        #pragma unroll
        for (int m = 0; m < 4; ++m)
            #pragma unroll
            for (int n = 0; n < 4; ++n) s[m][n] = zero;
        #pragma unroll
        for (int ks = 0; ks < 2; ++ks) {
            bf16x8 af[4], bfr[4];
            #pragma unroll
            for (int m = 0; m < 4; ++m)
                af[m] = *(const bf16x8*)((const char*)Qs +
                        (wq * 64 + m * 16 + lr) * 128 + (((ks * 4 + kg) ^ swz) << 4));
            #pragma unroll
            for (int n = 0; n < 4; ++n)
                bfr[n] = *(const bf16x8*)((const char*)Ks +
                        (wkv * 64 + n * 16 + lr) * 128 + (((ks * 4 + kg) ^ swz) << 4));
            #pragma unroll
            for (int m = 0; m < 4; ++m)
                #pragma unroll
                for (int n = 0; n < 4; ++n)
                    s[m][n] = __builtin_amdgcn_mfma_f32_16x16x32_bf16(
                        af[m], bfr[n], s[m][n], 0, 0, 0);
        }
        #pragma unroll
        for (int m = 0; m < 4; ++m)
            #pragma unroll
            for (int n = 0; n < 4; ++n)
                #pragma unroll
                for (int r = 0; r < 4; ++r)
                    rs[m][r] += __expf(s[m][n][r] * scale + sb);
    }

    #pragma unroll
    for (int m = 0; m < 4; ++m)
        #pragma unroll
        for (int r = 0; r < 4; ++r) {
            float sv = rs[m][r];
            sv += __shfl_xor(sv, 1); sv += __shfl_xor(sv, 2);
            sv += __shfl_xor(sv, 4); sv += __shfl_xor(sv, 8);
            if (lr == 0) red[wkv][wq * 64 + m * 16 + kg * 4 + r] = sv;
        }
    __syncthreads();
    if (tid < 128)
        sums[(size_t)z * L_ + bm + tid] = red[0][tid] + red[1][tid];
}

// ---------------------------------------------------------------------------
// Pass 2: per (z, q-tile 64): recompute S, E = exp(S)*inv, write normalized
// attn (streaming stores only), round-trip P through LDS, accumulate PV.
// ctx bf16 out [B*L, D].  LDS 56.5 KB -> 2 blocks/CU.
// ---------------------------------------------------------------------------
__global__ __launch_bounds__(256) void attn_fused(
    const unsigned short* __restrict__ qn, const unsigned short* __restrict__ kn,
    const unsigned short* __restrict__ Vt, const float* __restrict__ sums,
    const float* __restrict__ ls, const float* __restrict__ lb,
    float* __restrict__ attn, unsigned short* __restrict__ ctx)
{
    __shared__ __align__(16) unsigned short Qs[64 * 64];
    __shared__ __align__(16) unsigned short Ks[128 * 64];
    __shared__ __align__(16) unsigned short Vs[64 * 128];
    __shared__ __align__(16) unsigned short Ps[64 * 128];
    __shared__ float invs[64];
    const int z = blockIdx.y, b = z >> 4, h = z & 15;
    const unsigned short* Qp = qn + (size_t)b * L_ * D_ + h * DH_;
    const unsigned short* Kp = kn + (size_t)b * L_ * D_ + h * DH_;
    const unsigned short* Vp = Vt + (size_t)z * DH_ * L_;
    float* Cp = attn + (size_t)z * L_ * L_;
    unsigned short* Op = ctx + (size_t)b * L_ * D_ + h * DH_;

    const int tid  = threadIdx.x;
    const int bm   = blockIdx.x * 64;
    const int lane = tid & 63, wid = tid >> 6;
    const int wq   = wid >> 1, wkv = wid & 1;   // wkv doubles as d-half for PV
    const int kg   = lane >> 4, lr = lane & 15;
    const int swz  = lr & 7;

    #pragma unroll
    for (int i = 0; i < 2; ++i) {               // stage Q 64x64 once
        int c = i * 256 + tid, row = c >> 3, c8 = (c & 7) ^ (row & 7);
        gload_lds16(Qp + (size_t)(bm + row) * D_ + c8 * 8, (char*)Qs + c * 16);
    }
    if (tid < 64) invs[tid] = 1.0f / sums[(size_t)z * L_ + bm + tid];

    const float scale = expf(ls[0]);
    const float sb = lb[0];
    f32x4 zero = {0.f, 0.f, 0.f, 0.f};
    f32x4 cacc[2][2];
    #pragma unroll
    for (int m = 0; m < 2; ++m) { cacc[m][0] = zero; cacc[m][1] = zero; }

    for (int kv0 = 0; kv0 < L_; kv0 += 128) {
        __syncthreads();                        // prev PV reads done; Q/invs ready
        #pragma unroll
        for (int i = 0; i < 4; ++i) {           // K chunk: 128 kv x 64 d
            int c = i * 256 + tid, row = c >> 3, c8 = (c & 7) ^ (row & 7);
            gload_lds16(Kp + (size_t)(kv0 + row) * D_ + c8 * 8, (char*)Ks + c * 16);
        }
        #pragma unroll
        for (int i = 0; i < 4; ++i) {           // V chunk: 64 d x 128 kv
            int c = i * 256 + tid, row = c >> 4, cc = c & 15;
            int sc = cc ^ (row & 7);
            gload_lds16(Vp + (size_t)row * L_ + kv0 + sc * 8, (char*)Vs + c * 16);
        }
        __syncthreads();                        // staging visible

        // S quadrant: 32q x 64kv per wave
        f32x4 s[2][4];
        #pragma unroll
        for (int m = 0; m < 2; ++m)
            #pragma unroll
            for (int n = 0; n < 4; ++n) s[m][n] = zero;
        #pragma unroll
        for (int ks = 0; ks < 2; ++ks) {
            bf16x8 af[2], bfr[4];
            #pragma unroll
            for (int m = 0; m < 2; ++m)
                af[m] = *(const bf16x8*)((const char*)Qs +
                        (wq * 32 + m * 16 + lr) * 128 + (((ks * 4 + kg) ^ swz) << 4));
            #pragma unroll
            for (int n = 0; n < 4; ++n)
                bfr[n] = *(const bf16x8*)((const char*)Ks +
                        (wkv * 64 + n * 16 + lr) * 128 + (((ks * 4 + kg) ^ swz) << 4));
            #pragma unroll
            for (int m = 0; m < 2; ++m)
                #pragma unroll
                for (int n = 0; n < 4; ++n)
                    s[m][n] = __builtin_amdgcn_mfma_f32_16x16x32_bf16(
                        af[m], bfr[n], s[m][n], 0, 0, 0);
        }

        // normalize, write attn, stage P (bf16, chunk-XOR-swizzled rows)
        #pragma unroll
        for (int n = 0; n < 4; ++n) {
            #pragma unroll
            for (int m = 0; m < 2; ++m) {
                #pragma unroll
                for (int r = 0; r < 4; ++r) {
                    int row_l = wq * 32 + m * 16 + kg * 4 + r;
                    int col_l = wkv * 64 + n * 16 + lr;
                    float e = __expf(s[m][n][r] * scale + sb) * invs[row_l];
                    Cp[(size_t)(bm + row_l) * L_ + kv0 + col_l] = e;
                    int chunk = (col_l >> 3) ^ (row_l & 7);
                    Ps[row_l * 128 + chunk * 8 + (col_l & 7)] = f2bf(e);
                }
            }
        }
        __syncthreads();                        // Ps ready

        // PV: ctx quadrant 32q x 32d per wave, K = 128 kv
        #pragma unroll
        for (int k4 = 0; k4 < 4; ++k4) {
            bf16x8 pa[2], vb[2];
            #pragma unroll
            for (int m = 0; m < 2; ++m)
                pa[m] = *(const bf16x8*)((const char*)Ps +
                        (wq * 32 + m * 16 + lr) * 256 + (((k4 * 4 + kg) ^ swz) << 4));
            #pragma unroll
            for (int n = 0; n < 2; ++n)
                vb[n] = *(const bf16x8*)((const char*)Vs +
                        (wkv * 32 + n * 16 + lr) * 256 + (((k4 * 4 + kg) ^ swz) << 4));
            #pragma unroll
            for (int m = 0; m < 2; ++m)
                #pragma unroll
                for (int n = 0; n < 2; ++n)
                    cacc[m][n] = __builtin_amdgcn_mfma_f32_16x16x32_bf16(
                        pa[m], vb[n], cacc[m][n], 0, 0, 0);
        }
    }

    #pragma unroll
    for (int n = 0; n < 2; ++n) {
        const int col = wkv * 32 + n * 16 + lr;
        #pragma unroll
        for (int m = 0; m < 2; ++m) {
            const int row0 = bm + wq * 32 + m * 16 + kg * 4;
            #pragma unroll
            for (int r = 0; r < 4; ++r)
                Op[(size_t)(row0 + r) * D_ + col] = f2bf(cacc[m][n][r]);
        }
    }
}

// ---------------------------------------------------------------------------
// per-head transpose: v8 [B*L, D] -> Vt [B*H, DH, L]
// ---------------------------------------------------------------------------
__global__ __launch_bounds__(256) void transpose_v(
    const unsigned short* __restrict__ v8, unsigned short* __restrict__ Vt)
{
    __shared__ unsigned short tile[64][66];
    const int z = blockIdx.y, b = z >> 4, h = z & 15;
    const int t0 = blockIdx.x * 64;
    const unsigned short* src = v8 + ((size_t)(b * L_ + t0)) * D_ + h * DH_;
    unsigned short* dst = Vt + (size_t)z * DH_ * L_ + t0;
    const int t = threadIdx.x;
    #pragma unroll
    for (int i = 0; i < 2; ++i) {
        int c = i * 256 + t;
        int r = c >> 3, c8 = c & 7;
        u16x8 v = *(const u16x8*)(src + (size_t)r * D_ + c8 * 8);
        #pragma unroll
        for (int e = 0; e < 8; ++e) tile[r][c8 * 8 + e] = v[e];
    }
    __syncthreads();
    #pragma unroll
    for (int i = 0; i < 2; ++i) {
        int c = i * 256 + t;
        int d = c >> 3, c8 = c & 7;
        u16x8 v;
        #pragma unroll
        for (int e = 0; e < 8; ++e) v[e] = tile[c8 * 8 + e][d];
        *(u16x8*)(dst + (size_t)d * L_ + c8 * 8) = v;
    }
}

// ---------------------------------------------------------------------------
// in-place row L2-norm over D_ = 1024 bf16 (one block per row)
// ---------------------------------------------------------------------------
__global__ __launch_bounds__(256) void l2norm_bf16(unsigned short* __restrict__ x)
{
    unsigned short* row = x + (size_t)blockIdx.x * D_;
    const int tid = threadIdx.x;
    ushort4 v = ((ushort4*)row)[tid];
    float f0 = bf2f(v.x), f1 = bf2f(v.y), f2 = bf2f(v.z), f3 = bf2f(v.w);
    float ss = f0 * f0 + f1 * f1 + f2 * f2 + f3 * f3;
    #pragma unroll
    for (int off = 32; off >= 1; off >>= 1)
        ss += __shfl_xor(ss, off);
    __shared__ float red[4];
    const int lane = tid & 63, wid = tid >> 6;
    if (lane == 0) red[wid] = ss;
    __syncthreads();
    ss = red[0] + red[1] + red[2] + red[3];
    const float inv = rsqrtf(ss);
    ushort4 o;
    o.x = f2bf(f0 * inv); o.y = f2bf(f1 * inv);
    o.z = f2bf(f2 * inv); o.w = f2bf(f3 * inv);
    ((ushort4*)row)[tid] = o;
}

// ---------------------------------------------------------------------------
extern "C" void kernel_launch(void* const* d_in, const int* in_sizes, int n_in,
                              void* d_out, int out_size, void* d_ws, size_t ws_size,
                              hipStream_t stream)
{
    const float* query = (const float*)d_in[0];
    const float* key_  = (const float*)d_in[1];
    const float* value = (const float*)d_in[2];
    const float* ls    = (const float*)d_in[3];
    const float* lb    = (const float*)d_in[4];
    const float* Wq    = (const float*)d_in[5];
    const float* bq    = (const float*)d_in[6];
    const float* Wk    = (const float*)d_in[7];
    const float* bk    = (const float*)d_in[8];
    const float* Wv    = (const float*)d_in[9];
    const float* bv    = (const float*)d_in[10];
    const float* Wo    = (const float*)d_in[11];
    const float* bo    = (const float*)d_in[12];

    float* out  = (float*)d_out;                     // [B, L, D]
    float* attn = out + (size_t)M_TOT * D_;          // [B, H, L, L] fp32

    // workspace: 48 MB total
    unsigned short* xb = (unsigned short*)d_ws;                  // 8 MB cast input
    unsigned short* Wb = xb + (size_t)M_TOT * D_;                // 8 MB (4 x 1M bf16)
    unsigned short* q8 = Wb + (size_t)4 * D_ * D_;               // 8 MB
    unsigned short* k8 = q8 + (size_t)M_TOT * D_;                // 8 MB
    unsigned short* v8 = k8 + (size_t)M_TOT * D_;                // 8 MB
    unsigned short* Vt = v8 + (size_t)M_TOT * D_;                // 8 MB
    unsigned short* ctxb = xb;                                   // reuse (xb dead)
    float* sums = (float*)v8;     // 256 KB row sums; v8 dead after transpose_v

    dim3 blk(256);
    const dim3 gproj(M_TOT / 128, D_ / 128);         // 32 x 8

    cast_w4<<<dim3(D_ * D_ / 8 / 256, 4), blk, 0, stream>>>(Wq, Wk, Wv, Wo, (u16x8*)Wb);

    cast_in<<<M_TOT * D_ / 8 / 256, blk, 0, stream>>>(query, (u16x8*)xb);
    gemm_nt_mfma<false><<<gproj, blk, 0, stream>>>(xb, Wb + 0 * (size_t)D_ * D_, bq, q8, D_, D_);
    cast_in<<<M_TOT * D_ / 8 / 256, blk, 0, stream>>>(key_, (u16x8*)xb);
    gemm_nt_mfma<false><<<gproj, blk, 0, stream>>>(xb, Wb + 1 * (size_t)D_ * D_, bk, k8, D_, D_);
    cast_in<<<M_TOT * D_ / 8 / 256, blk, 0, stream>>>(value, (u16x8*)xb);
    gemm_nt_mfma<false><<<gproj, blk, 0, stream>>>(xb, Wb + 2 * (size_t)D_ * D_, bv, v8, D_, D_);

    l2norm_bf16<<<dim3(M_TOT), blk, 0, stream>>>(q8);
    l2norm_bf16<<<dim3(M_TOT), blk, 0, stream>>>(k8);

    transpose_v<<<dim3(L_ / 64, B_ * H_), blk, 0, stream>>>(v8, Vt);

    attn_sums<<<dim3(L_ / 128, B_ * H_), blk, 0, stream>>>(q8, k8, ls, lb, sums);

    attn_fused<<<dim3(L_ / 64, B_ * H_), blk, 0, stream>>>(
        q8, k8, Vt, sums, ls, lb, attn, ctxb);

    gemm_nt_mfma<true><<<gproj, blk, 0, stream>>>(ctxb, Wb + 3 * (size_t)D_ * D_, bo, out, D_, D_);
}

// Round 7
// 801.226 us; speedup vs baseline: 1.2560x; 1.0316x over previous
//
#include <hip/hip_runtime.h>

#define B_   2
#define L_   2048
#define D_   1024
#define H_   16
#define DH_  64
#define M_TOT (B_ * L_)   // 4096

typedef __attribute__((ext_vector_type(8))) __bf16 bf16x8;
typedef __attribute__((ext_vector_type(4))) float f32x4;
typedef __attribute__((ext_vector_type(8))) unsigned short u16x8;

// round-to-nearest-even fp32 -> bf16
__device__ __forceinline__ unsigned short f2bf(float f) {
    unsigned int u = __float_as_uint(f);
    u += 0x7fffu + ((u >> 16) & 1u);
    return (unsigned short)(u >> 16);
}
__device__ __forceinline__ float bf2f(unsigned short u) {
    return __uint_as_float(((unsigned int)u) << 16);
}

// async 16B global -> LDS (dest = wave-uniform base + lane*16)
__device__ __forceinline__ void gload_lds16(const void* g, void* l) {
    __builtin_amdgcn_global_load_lds(
        (__attribute__((address_space(1))) void*)(void*)g,
        (__attribute__((address_space(3))) void*)l, 16, 0, 0);
}

// ---------------------------------------------------------------------------
// casts
// ---------------------------------------------------------------------------
__global__ __launch_bounds__(256) void cast_in(const float* __restrict__ src,
                                               u16x8* __restrict__ dst)
{
    const int i = blockIdx.x * 256 + threadIdx.x;
    const float4* s = (const float4*)src;
    float4 a = s[2 * i], b = s[2 * i + 1];
    u16x8 w;
    w[0] = f2bf(a.x); w[1] = f2bf(a.y); w[2] = f2bf(a.z); w[3] = f2bf(a.w);
    w[4] = f2bf(b.x); w[5] = f2bf(b.y); w[6] = f2bf(b.z); w[7] = f2bf(b.w);
    dst[i] = w;
}

__global__ __launch_bounds__(256) void cast_w4(const float* __restrict__ Wq,
                                               const float* __restrict__ Wk,
                                               const float* __restrict__ Wv,
                                               const float* __restrict__ Wo,
                                               u16x8* __restrict__ dst)
{
    const int y = blockIdx.y;
    const float* src = (y == 0) ? Wq : (y == 1) ? Wk : (y == 2) ? Wv : Wo;
    const int i = blockIdx.x * 256 + threadIdx.x;
    const float4* s = (const float4*)src;
    float4 a = s[2 * i], b = s[2 * i + 1];
    u16x8 w;
    w[0] = f2bf(a.x); w[1] = f2bf(a.y); w[2] = f2bf(a.z); w[3] = f2bf(a.w);
    w[4] = f2bf(b.x); w[5] = f2bf(b.y); w[6] = f2bf(b.z); w[7] = f2bf(b.w);
    dst[(size_t)y * (D_ * D_ / 8) + i] = w;
}

// ---------------------------------------------------------------------------
// NT MFMA GEMM: C[M,N] = A[M,K] * W[N,K]^T + bias[N], bf16 in.
// 128x64 tile, BK=64, double-buffered staging, 1 barrier/iter, 3 blk/CU.
// ---------------------------------------------------------------------------
template<bool F32OUT>
__global__ __launch_bounds__(256, 3) void gemm_nt_mfma(
    const unsigned short* __restrict__ A, const unsigned short* __restrict__ W,
    const float* __restrict__ bias, void* __restrict__ Cout, int K, int N)
{
    __shared__ __align__(16) unsigned short As[2][128 * 64];  // 32K
    __shared__ __align__(16) unsigned short Bs[2][64 * 64];   // 16K
    const int tid  = threadIdx.x;
    const int bm   = blockIdx.x * 128;
    const int bn   = blockIdx.y * 64;
    const int lane = tid & 63, wid = tid >> 6;
    const int wm   = (wid >> 1) * 64, wn = (wid & 1) * 32;
    const int kg   = lane >> 4, lr = lane & 15;
    const int swz  = lr & 7;

    f32x4 zero = {0.f, 0.f, 0.f, 0.f};
    f32x4 acc[4][2];
    #pragma unroll
    for (int m = 0; m < 4; ++m) { acc[m][0] = zero; acc[m][1] = zero; }

    // prologue stage (tile 0 -> buf 0)
    #pragma unroll
    for (int i = 0; i < 4; ++i) {
        int c = i * 256 + tid, row = c >> 3, c8 = (c & 7) ^ (row & 7);
        gload_lds16(A + (size_t)(bm + row) * K + c8 * 8, (char*)As[0] + c * 16);
    }
    #pragma unroll
    for (int i = 0; i < 2; ++i) {
        int c = i * 256 + tid, row = c >> 3, c8 = (c & 7) ^ (row & 7);
        gload_lds16(W + (size_t)(bn + row) * K + c8 * 8, (char*)Bs[0] + c * 16);
    }

    const int nIt = K / 64;
    int cur = 0;
    for (int it = 0; it < nIt; ++it) {
        __syncthreads();                       // buf[cur] staged; prev reads done
        if (it + 1 < nIt) {
            const int k0 = (it + 1) * 64;
            #pragma unroll
            for (int i = 0; i < 4; ++i) {
                int c = i * 256 + tid, row = c >> 3, c8 = (c & 7) ^ (row & 7);
                gload_lds16(A + (size_t)(bm + row) * K + k0 + c8 * 8,
                            (char*)As[cur ^ 1] + c * 16);
            }
            #pragma unroll
            for (int i = 0; i < 2; ++i) {
                int c = i * 256 + tid, row = c >> 3, c8 = (c & 7) ^ (row & 7);
                gload_lds16(W + (size_t)(bn + row) * K + k0 + c8 * 8,
                            (char*)Bs[cur ^ 1] + c * 16);
            }
        }
        #pragma unroll
        for (int ks = 0; ks < 2; ++ks) {
            bf16x8 af[4], bfr[2];
            #pragma unroll
            for (int m = 0; m < 4; ++m)
                af[m] = *(const bf16x8*)((const char*)As[cur] +
                        (wm + m * 16 + lr) * 128 + (((ks * 4 + kg) ^ swz) << 4));
            #pragma unroll
            for (int n = 0; n < 2; ++n)
                bfr[n] = *(const bf16x8*)((const char*)Bs[cur] +
                        (wn + n * 16 + lr) * 128 + (((ks * 4 + kg) ^ swz) << 4));
            #pragma unroll
            for (int m = 0; m < 4; ++m)
                #pragma unroll
                for (int n = 0; n < 2; ++n)
                    acc[m][n] = __builtin_amdgcn_mfma_f32_16x16x32_bf16(
                        af[m], bfr[n], acc[m][n], 0, 0, 0);
        }
        cur ^= 1;
    }

    // C/D layout: col = lane&15, row = (lane>>4)*4 + reg
    #pragma unroll
    for (int n = 0; n < 2; ++n) {
        const int col = bn + wn + n * 16 + lr;
        const float bv = bias[col];
        #pragma unroll
        for (int m = 0; m < 4; ++m) {
            const int row0 = bm + wm + m * 16 + kg * 4;
            #pragma unroll
            for (int r = 0; r < 4; ++r) {
                float val = acc[m][n][r] + bv;
                if (F32OUT)
                    ((float*)Cout)[(size_t)(row0 + r) * N + col] = val;
                else
                    ((unsigned short*)Cout)[(size_t)(row0 + r) * N + col] = f2bf(val);
            }
        }
    }
}

// ---------------------------------------------------------------------------
// Pass 1: per (z, q-tile 128): row sums of exp(scale*(q.k)+bias) over all kv.
// Double-buffered K staging, 1 barrier/iter. 1D grid 512, z-per-XCD swizzle.
// ---------------------------------------------------------------------------
__global__ __launch_bounds__(256, 3) void attn_sums(
    const unsigned short* __restrict__ qn, const unsigned short* __restrict__ kn,
    const float* __restrict__ ls, const float* __restrict__ lb,
    float* __restrict__ sums)
{
    __shared__ __align__(16) unsigned short Qs[128 * 64];     // 16K
    __shared__ __align__(16) unsigned short Ks[2][128 * 64];  // 32K
    __shared__ float red[2][128];
    const int flat = blockIdx.x;                  // 512
    const int z  = (flat & 7) * 4 + ((flat >> 3) & 3);
    const int qt = flat >> 5;                     // 0..15
    const int b = z >> 4, h = z & 15;
    const unsigned short* Qp = qn + (size_t)b * L_ * D_ + h * DH_;
    const unsigned short* Kp = kn + (size_t)b * L_ * D_ + h * DH_;

    const int tid = threadIdx.x;
    const int bm  = qt * 128;
    const int lane = tid & 63, wid = tid >> 6;
    const int wq = wid >> 1, wkv = wid & 1;
    const int kg = lane >> 4, lr = lane & 15;
    const int swz = lr & 7;

    #pragma unroll
    for (int i = 0; i < 4; ++i) {
        int c = i * 256 + tid, row = c >> 3, c8 = (c & 7) ^ (row & 7);
        gload_lds16(Qp + (size_t)(bm + row) * D_ + c8 * 8, (char*)Qs + c * 16);
    }
    #pragma unroll
    for (int i = 0; i < 4; ++i) {                 // K tile 0 -> buf 0
        int c = i * 256 + tid, row = c >> 3, c8 = (c & 7) ^ (row & 7);
        gload_lds16(Kp + (size_t)row * D_ + c8 * 8, (char*)Ks[0] + c * 16);
    }

    const float scale = expf(ls[0]);
    const float sb = lb[0];
    f32x4 zero = {0.f, 0.f, 0.f, 0.f};
    float rs[4][4] = {};
    int cur = 0;

    for (int it = 0; it < L_ / 128; ++it) {
        __syncthreads();
        if (it + 1 < L_ / 128) {
            const int kv = (it + 1) * 128;
            #pragma unroll
            for (int i = 0; i < 4; ++i) {
                int c = i * 256 + tid, row = c >> 3, c8 = (c & 7) ^ (row & 7);
                gload_lds16(Kp + (size_t)(kv + row) * D_ + c8 * 8,
                            (char*)Ks[cur ^ 1] + c * 16);
            }
        }
        f32x4 s[4][4];
        #pragma unroll
        for (int m = 0; m < 4; ++m)
            #pragma unroll
            for (int n = 0; n < 4; ++n) s[m][n] = zero;
        #pragma unroll
        for (int ks = 0; ks < 2; ++ks) {
            bf16x8 af[4], bfr[4];
            #pragma unroll
            for (int m = 0; m < 4; ++m)
                af[m] = *(const bf16x8*)((const char*)Qs +
                        (wq * 64 + m * 16 + lr) * 128 + (((ks * 4 + kg) ^ swz) << 4));
            #pragma unroll
            for (int n = 0; n < 4; ++n)
                bfr[n] = *(const bf16x8*)((const char*)Ks[cur] +
                        (wkv * 64 + n * 16 + lr) * 128 + (((ks * 4 + kg) ^ swz) << 4));
            #pragma unroll
            for (int m = 0; m < 4; ++m)
                #pragma unroll
                for (int n = 0; n < 4; ++n)
                    s[m][n] = __builtin_amdgcn_mfma_f32_16x16x32_bf16(
                        af[m], bfr[n], s[m][n], 0, 0, 0);
        }
        #pragma unroll
        for (int m = 0; m < 4; ++m)
            #pragma unroll
            for (int n = 0; n < 4; ++n)
                #pragma unroll
                for (int r = 0; r < 4; ++r)
                    rs[m][r] += __expf(s[m][n][r] * scale + sb);
        cur ^= 1;
    }

    #pragma unroll
    for (int m = 0; m < 4; ++m)
        #pragma unroll
        for (int r = 0; r < 4; ++r) {
            float sv = rs[m][r];
            sv += __shfl_xor(sv, 1); sv += __shfl_xor(sv, 2);
            sv += __shfl_xor(sv, 4); sv += __shfl_xor(sv, 8);
            if (lr == 0) red[wkv][wq * 64 + m * 16 + kg * 4 + r] = sv;
        }
    __syncthreads();
    if (tid < 128)
        sums[(size_t)z * L_ + bm + tid] = red[0][tid] + red[1][tid];
}

// ---------------------------------------------------------------------------
// Pass 2: per (z, q-tile 64): recompute S, E = exp(S)*inv, write normalized
// attn; per-wave kv-quadrant PV (wave-private P round-trip, NO mid barrier);
// double-buffered K/V, 1 barrier/iter; cross-wkv ctx reduction at end.
// ---------------------------------------------------------------------------
__global__ __launch_bounds__(256, 3) void attn_fused(
    const unsigned short* __restrict__ qn, const unsigned short* __restrict__ kn,
    const unsigned short* __restrict__ Vt, const float* __restrict__ sums,
    const float* __restrict__ ls, const float* __restrict__ lb,
    float* __restrict__ attn, unsigned short* __restrict__ ctx)
{
    __shared__ __align__(16) unsigned short Qs[64 * 64];      // 8K
    __shared__ __align__(16) unsigned short Ks[2][64 * 64];   // 16K
    __shared__ __align__(16) unsigned short Vs[2][64 * 64];   // 16K
    __shared__ __align__(16) unsigned short Ps[64 * 64];      // 8K (wave-private quads)
    __shared__ float invs[64];
    const int flat = blockIdx.x;                  // 1024
    const int z  = (flat & 7) * 4 + ((flat >> 3) & 3);
    const int qt = flat >> 5;                     // 0..31
    const int b = z >> 4, h = z & 15;
    const unsigned short* Qp = qn + (size_t)b * L_ * D_ + h * DH_;
    const unsigned short* Kp = kn + (size_t)b * L_ * D_ + h * DH_;
    const unsigned short* Vp = Vt + (size_t)z * DH_ * L_;
    float* Cp = attn + (size_t)z * L_ * L_;
    unsigned short* Op = ctx + (size_t)b * L_ * D_ + h * DH_;

    const int tid = threadIdx.x;
    const int bm  = qt * 64;
    const int lane = tid & 63, wid = tid >> 6;
    const int wq = wid >> 1, wkv = wid & 1;       // kv-half for S and PV
    const int kg = lane >> 4, lr = lane & 15;
    const int swz = lr & 7;

    #pragma unroll
    for (int i = 0; i < 2; ++i) {                 // Q 64x64 once
        int c = i * 256 + tid, row = c >> 3, c8 = (c & 7) ^ (row & 7);
        gload_lds16(Qp + (size_t)(bm + row) * D_ + c8 * 8, (char*)Qs + c * 16);
    }
    #pragma unroll
    for (int i = 0; i < 2; ++i) {                 // K tile0 (64 kv x 64 d)
        int c = i * 256 + tid, row = c >> 3, c8 = (c & 7) ^ (row & 7);
        gload_lds16(Kp + (size_t)row * D_ + c8 * 8, (char*)Ks[0] + c * 16);
    }
    #pragma unroll
    for (int i = 0; i < 2; ++i) {                 // V tile0 (64 d x 64 kv)
        int c = i * 256 + tid, row = c >> 3, c8 = (c & 7) ^ (row & 7);
        gload_lds16(Vp + (size_t)row * L_ + c8 * 8, (char*)Vs[0] + c * 16);
    }
    if (tid < 64) invs[tid] = 1.0f / sums[(size_t)z * L_ + bm + tid];

    const float scale = expf(ls[0]);
    const float sb = lb[0];
    f32x4 zero = {0.f, 0.f, 0.f, 0.f};
    f32x4 cacc[2][4];
    #pragma unroll
    for (int m = 0; m < 2; ++m)
        #pragma unroll
        for (int n = 0; n < 4; ++n) cacc[m][n] = zero;

    int cur = 0;
    for (int it = 0; it < L_ / 64; ++it) {
        __syncthreads();                          // buf[cur] staged; prev reads done
        if (it + 1 < L_ / 64) {                   // prefetch overlaps whole phase
            const int kv = (it + 1) * 64;
            #pragma unroll
            for (int i = 0; i < 2; ++i) {
                int c = i * 256 + tid, row = c >> 3, c8 = (c & 7) ^ (row & 7);
                gload_lds16(Kp + (size_t)(kv + row) * D_ + c8 * 8,
                            (char*)Ks[cur ^ 1] + c * 16);
            }
            #pragma unroll
            for (int i = 0; i < 2; ++i) {
                int c = i * 256 + tid, row = c >> 3, c8 = (c & 7) ^ (row & 7);
                gload_lds16(Vp + (size_t)row * L_ + kv + c8 * 8,
                            (char*)Vs[cur ^ 1] + c * 16);
            }
        }

        // S quadrant: 32q x 32kv per wave
        f32x4 s[2][2];
        #pragma unroll
        for (int m = 0; m < 2; ++m) { s[m][0] = zero; s[m][1] = zero; }
        #pragma unroll
        for (int ks = 0; ks < 2; ++ks) {
            bf16x8 af[2], bfr[2];
            #pragma unroll
            for (int m = 0; m < 2; ++m)
                af[m] = *(const bf16x8*)((const char*)Qs +
                        (wq * 32 + m * 16 + lr) * 128 + (((ks * 4 + kg) ^ swz) << 4));
            #pragma unroll
            for (int n = 0; n < 2; ++n)
                bfr[n] = *(const bf16x8*)((const char*)Ks[cur] +
                        (wkv * 32 + n * 16 + lr) * 128 + (((ks * 4 + kg) ^ swz) << 4));
            #pragma unroll
            for (int m = 0; m < 2; ++m)
                #pragma unroll
                for (int n = 0; n < 2; ++n)
                    s[m][n] = __builtin_amdgcn_mfma_f32_16x16x32_bf16(
                        af[m], bfr[n], s[m][n], 0, 0, 0);
        }

        // exp, normalize, attn store, wave-private Ps stage
        const int kv0 = it * 64;
        #pragma unroll
        for (int m = 0; m < 2; ++m) {
            #pragma unroll
            for (int n = 0; n < 2; ++n) {
                #pragma unroll
                for (int r = 0; r < 4; ++r) {
                    const int row_l = wq * 32 + m * 16 + kg * 4 + r;
                    const int col_l = wkv * 32 + n * 16 + lr;
                    float e = __expf(s[m][n][r] * scale + sb) * invs[row_l];
                    Cp[(size_t)(bm + row_l) * L_ + kv0 + col_l] = e;
                    Ps[row_l * 64 + (((col_l >> 3) ^ (row_l & 7)) << 3) + (col_l & 7)]
                        = f2bf(e);
                }
            }
        }
        asm volatile("s_waitcnt lgkmcnt(0)" ::: "memory");
        __builtin_amdgcn_sched_barrier(0);

        // PV: own kv-half (K=32, one k-step); partial ctx 32q x 64d
        {
            bf16x8 pa[2], vb[4];
            #pragma unroll
            for (int m = 0; m < 2; ++m)
                pa[m] = *(const bf16x8*)((const char*)Ps +
                        (wq * 32 + m * 16 + lr) * 128 + (((wkv * 4 + kg) ^ swz) << 4));
            #pragma unroll
            for (int n = 0; n < 4; ++n)
                vb[n] = *(const bf16x8*)((const char*)Vs[cur] +
                        (n * 16 + lr) * 128 + (((wkv * 4 + kg) ^ swz) << 4));
            #pragma unroll
            for (int m = 0; m < 2; ++m)
                #pragma unroll
                for (int n = 0; n < 4; ++n)
                    cacc[m][n] = __builtin_amdgcn_mfma_f32_16x16x32_bf16(
                        pa[m], vb[n], cacc[m][n], 0, 0, 0);
        }
        cur ^= 1;
    }

    // cross-wkv reduction of ctx partials (reuse Ks as 16K fp32 scratch)
    __syncthreads();
    float* redp = (float*)Ks;
    if (wkv == 1) {
        #pragma unroll
        for (int m = 0; m < 2; ++m)
            #pragma unroll
            for (int n = 0; n < 4; ++n)
                #pragma unroll
                for (int r = 0; r < 4; ++r)
                    redp[(wq * 32 + m * 16 + kg * 4 + r) * 64 + n * 16 + lr]
                        = cacc[m][n][r];
    }
    __syncthreads();
    if (wkv == 0) {
        #pragma unroll
        for (int m = 0; m < 2; ++m) {
            #pragma unroll
            for (int n = 0; n < 4; ++n) {
                #pragma unroll
                for (int r = 0; r < 4; ++r) {
                    const int row_l = wq * 32 + m * 16 + kg * 4 + r;
                    const int col   = n * 16 + lr;
                    float val = cacc[m][n][r] + redp[row_l * 64 + col];
                    Op[(size_t)(bm + row_l) * D_ + col] = f2bf(val);
                }
            }
        }
    }
}

// ---------------------------------------------------------------------------
// per-head transpose: v8 [B*L, D] -> Vt [B*H, DH, L]
// ---------------------------------------------------------------------------
__global__ __launch_bounds__(256) void transpose_v(
    const unsigned short* __restrict__ v8, unsigned short* __restrict__ Vt)
{
    __shared__ unsigned short tile[64][66];
    const int z = blockIdx.y, b = z >> 4, h = z & 15;
    const int t0 = blockIdx.x * 64;
    const unsigned short* src = v8 + ((size_t)(b * L_ + t0)) * D_ + h * DH_;
    unsigned short* dst = Vt + (size_t)z * DH_ * L_ + t0;
    const int t = threadIdx.x;
    #pragma unroll
    for (int i = 0; i < 2; ++i) {
        int c = i * 256 + t;
        int r = c >> 3, c8 = c & 7;
        u16x8 v = *(const u16x8*)(src + (size_t)r * D_ + c8 * 8);
        #pragma unroll
        for (int e = 0; e < 8; ++e) tile[r][c8 * 8 + e] = v[e];
    }
    __syncthreads();
    #pragma unroll
    for (int i = 0; i < 2; ++i) {
        int c = i * 256 + t;
        int d = c >> 3, c8 = c & 7;
        u16x8 v;
        #pragma unroll
        for (int e = 0; e < 8; ++e) v[e] = tile[c8 * 8 + e][d];
        *(u16x8*)(dst + (size_t)d * L_ + c8 * 8) = v;
    }
}

// ---------------------------------------------------------------------------
// in-place row L2-norm over D_ = 1024 bf16; y=0 -> q8, y=1 -> k8
// ---------------------------------------------------------------------------
__global__ __launch_bounds__(256) void l2norm2(unsigned short* __restrict__ q8,
                                               unsigned short* __restrict__ k8)
{
    unsigned short* base = blockIdx.y ? k8 : q8;
    unsigned short* row = base + (size_t)blockIdx.x * D_;
    const int tid = threadIdx.x;
    ushort4 v = ((ushort4*)row)[tid];
    float f0 = bf2f(v.x), f1 = bf2f(v.y), f2 = bf2f(v.z), f3 = bf2f(v.w);
    float ss = f0 * f0 + f1 * f1 + f2 * f2 + f3 * f3;
    #pragma unroll
    for (int off = 32; off >= 1; off >>= 1)
        ss += __shfl_xor(ss, off);
    __shared__ float red[4];
    const int lane = tid & 63, wid = tid >> 6;
    if (lane == 0) red[wid] = ss;
    __syncthreads();
    ss = red[0] + red[1] + red[2] + red[3];
    const float inv = rsqrtf(ss);
    ushort4 o;
    o.x = f2bf(f0 * inv); o.y = f2bf(f1 * inv);
    o.z = f2bf(f2 * inv); o.w = f2bf(f3 * inv);
    ((ushort4*)row)[tid] = o;
}

// ---------------------------------------------------------------------------
extern "C" void kernel_launch(void* const* d_in, const int* in_sizes, int n_in,
                              void* d_out, int out_size, void* d_ws, size_t ws_size,
                              hipStream_t stream)
{
    const float* query = (const float*)d_in[0];
    const float* key_  = (const float*)d_in[1];
    const float* value = (const float*)d_in[2];
    const float* ls    = (const float*)d_in[3];
    const float* lb    = (const float*)d_in[4];
    const float* Wq    = (const float*)d_in[5];
    const float* bq    = (const float*)d_in[6];
    const float* Wk    = (const float*)d_in[7];
    const float* bk    = (const float*)d_in[8];
    const float* Wv    = (const float*)d_in[9];
    const float* bv    = (const float*)d_in[10];
    const float* Wo    = (const float*)d_in[11];
    const float* bo    = (const float*)d_in[12];

    float* out  = (float*)d_out;                     // [B, L, D]
    float* attn = out + (size_t)M_TOT * D_;          // [B, H, L, L] fp32

    // workspace: 48 MB total
    unsigned short* xb = (unsigned short*)d_ws;                  // 8 MB cast input
    unsigned short* Wb = xb + (size_t)M_TOT * D_;                // 8 MB (4 x 1M bf16)
    unsigned short* q8 = Wb + (size_t)4 * D_ * D_;               // 8 MB
    unsigned short* k8 = q8 + (size_t)M_TOT * D_;                // 8 MB
    unsigned short* v8 = k8 + (size_t)M_TOT * D_;                // 8 MB
    unsigned short* Vt = v8 + (size_t)M_TOT * D_;                // 8 MB
    unsigned short* ctxb = xb;                                   // reuse (xb dead)
    float* sums = (float*)v8;     // 256 KB row sums; v8 dead after transpose_v

    dim3 blk(256);
    const dim3 gproj(M_TOT / 128, D_ / 64);          // 32 x 16 = 512 blocks

    cast_w4<<<dim3(D_ * D_ / 8 / 256, 4), blk, 0, stream>>>(Wq, Wk, Wv, Wo, (u16x8*)Wb);

    cast_in<<<M_TOT * D_ / 8 / 256, blk, 0, stream>>>(query, (u16x8*)xb);
    gemm_nt_mfma<false><<<gproj, blk, 0, stream>>>(xb, Wb + 0 * (size_t)D_ * D_, bq, q8, D_, D_);
    cast_in<<<M_TOT * D_ / 8 / 256, blk, 0, stream>>>(key_, (u16x8*)xb);
    gemm_nt_mfma<false><<<gproj, blk, 0, stream>>>(xb, Wb + 1 * (size_t)D_ * D_, bk, k8, D_, D_);
    cast_in<<<M_TOT * D_ / 8 / 256, blk, 0, stream>>>(value, (u16x8*)xb);
    gemm_nt_mfma<false><<<gproj, blk, 0, stream>>>(xb, Wb + 2 * (size_t)D_ * D_, bv, v8, D_, D_);

    l2norm2<<<dim3(M_TOT, 2), blk, 0, stream>>>(q8, k8);

    transpose_v<<<dim3(L_ / 64, B_ * H_), blk, 0, stream>>>(v8, Vt);

    attn_sums<<<dim3(512), blk, 0, stream>>>(q8, k8, ls, lb, sums);

    attn_fused<<<dim3(1024), blk, 0, stream>>>(q8, k8, Vt, sums, ls, lb, attn, ctxb);

    gemm_nt_mfma<true><<<gproj, blk, 0, stream>>>(ctxb, Wb + 3 * (size_t)D_ * D_, bo, out, D_, D_);
}